// Round 1
// 107.060 us; speedup vs baseline: 1.0024x; 1.0024x over previous
//
#include <hip/hip_runtime.h>

#define NPTS 8192
#define NSL 64          // j-slices (128 points each)
#define HF 96.0f

// Workspace layout (bytes):
//   0        : float  nn2p[64][8192]   partial min d2 (unclamped) per (slice, i)
//   2097152  : int    rkp [64][8192]   partial pz-rank per (slice, i)
//   4194304  : float2 pxy[8192]        (px,py) sorted by pz
//   4259840  : float  pzs[8192]
//   4292608  : double sum_part[32]     per-block partial sums of nn_dist
//   4325376  : float  sx[8192]         SoA: x*HF
//   4358144  : float  sy[8192]
//   4390912  : float  sz[8192]
//   4423680  : float  ssq[8192]        x^2+y^2+z^2
//   4456448  : u64    skey[8192]       monotone (z, idx) sort key
// No init kernel / atomics: every cell written exactly once.
// Session lessons: coop grid.sync ~100us/sync (R7) -> keep separate launches.
// 16-col k_median regressed (R8) -> keep 8-col.
// R(this): k_nn_rank was DS-broadcast-bound (2 LDS broadcasts per wave-iter on the
// per-CU DS pipe). j-operands are wave-uniform -> feed them through the SCALAR pipe
// (s_load from SoA, uniform float4/ulonglong2 loads) and drop LDS entirely.

// monotone (z, idx) -> u64 key; strict total order, one u64 compare per pair
__device__ __forceinline__ unsigned long long zkey(float z, int idx) {
    unsigned u = __float_as_uint(z);
    unsigned m = (unsigned)((int)u >> 31) | 0x80000000u;  // neg: FFFFFFFF, pos: 80000000
    return ((unsigned long long)(u ^ m) << 13) | (unsigned)idx;
}

// SoA prep: 32 blocks x 256. Bit-identical values to what k_nn_rank computed before.
__global__ __launch_bounds__(256) void k_soa(const float* __restrict__ pts,
                                             float* __restrict__ sx,
                                             float* __restrict__ sy,
                                             float* __restrict__ sz,
                                             float* __restrict__ ssq,
                                             unsigned long long* __restrict__ skey) {
    const int i = blockIdx.x * 256 + threadIdx.x;
    const float x = pts[3 * i + 0] * HF;
    const float y = pts[3 * i + 1] * HF;
    const float z = pts[3 * i + 2] * HF;
    sx[i] = x; sy[i] = y; sz[i] = z;
    ssq[i] = x * x + y * y + z * z;
    skey[i] = zkey(z, i);
}

// grid (32 i-blocks, 64 j-slices of 128), block 256 -> 2048 blocks, 8/CU.
// j-operands are wave-uniform: loaded as uniform float4/ulonglong2 -> compiler
// emits s_load_dwordx4/x8 (scalar cache), zero DS/VMEM pressure in the hot loop.
__global__ __launch_bounds__(256) void k_nn_rank(const float* __restrict__ sx,
                                                 const float* __restrict__ sy,
                                                 const float* __restrict__ sz,
                                                 const float* __restrict__ ssq,
                                                 const unsigned long long* __restrict__ skey,
                                                 float* __restrict__ nn2p,
                                                 int* __restrict__ rkp) {
    const int tid = threadIdx.x;
    const int bx = blockIdx.x, by = blockIdx.y;
    const int i = bx * 256 + tid;

    const float xi = sx[i], yi = sy[i], zi = sz[i], sqi = ssq[i];
    const unsigned long long ki = skey[i];

    // uniform (wave-invariant) j-slice base pointers, 16B-aligned
    const float4* __restrict__ vx = (const float4*)sx + by * 32;
    const float4* __restrict__ vy = (const float4*)sy + by * 32;
    const float4* __restrict__ vz = (const float4*)sz + by * 32;
    const float4* __restrict__ vq = (const float4*)ssq + by * 32;
    const ulonglong2* __restrict__ vk = (const ulonglong2*)skey + by * 64;

    float mn = 3.0e38f;
    int rk = 0;
    // self-pair occurs iff this j-slice covers i; condition is wave-uniform
    // (tid>>7 constant within a wave), so no divergence between loop versions.
    const bool has_self = (by == 2 * bx + (tid >> 7));
    if (!has_self) {
        #pragma unroll 4
        for (int kb = 0; kb < 32; ++kb) {
            const float4 X = vx[kb], Y = vy[kb], Z = vz[kb], Q = vq[kb];
            const ulonglong2 K0 = vk[2 * kb], K1 = vk[2 * kb + 1];
            float d2;
            // reference formula: sq_i + sq_j - 2*dot
            d2 = sqi + Q.x - 2.0f * (xi * X.x + yi * Y.x + zi * Z.x); mn = fminf(mn, d2); rk += (int)(K0.x < ki);
            d2 = sqi + Q.y - 2.0f * (xi * X.y + yi * Y.y + zi * Z.y); mn = fminf(mn, d2); rk += (int)(K0.y < ki);
            d2 = sqi + Q.z - 2.0f * (xi * X.z + yi * Y.z + zi * Z.z); mn = fminf(mn, d2); rk += (int)(K1.x < ki);
            d2 = sqi + Q.w - 2.0f * (xi * X.w + yi * Y.w + zi * Z.w); mn = fminf(mn, d2); rk += (int)(K1.y < ki);
        }
    } else {
        const int self_k = tid & 127;   // j - j0 of the self pair (per-lane)
        #pragma unroll 4
        for (int kb = 0; kb < 32; ++kb) {
            const float4 X = vx[kb], Y = vy[kb], Z = vz[kb], Q = vq[kb];
            const ulonglong2 K0 = vk[2 * kb], K1 = vk[2 * kb + 1];
            const int e = kb * 4;
            float d2;
            d2 = sqi + Q.x - 2.0f * (xi * X.x + yi * Y.x + zi * Z.x); if (e + 0 != self_k) mn = fminf(mn, d2); rk += (int)(K0.x < ki);
            d2 = sqi + Q.y - 2.0f * (xi * X.y + yi * Y.y + zi * Z.y); if (e + 1 != self_k) mn = fminf(mn, d2); rk += (int)(K0.y < ki);
            d2 = sqi + Q.z - 2.0f * (xi * X.z + yi * Y.z + zi * Z.z); if (e + 2 != self_k) mn = fminf(mn, d2); rk += (int)(K1.x < ki);
            d2 = sqi + Q.w - 2.0f * (xi * X.w + yi * Y.w + zi * Z.w); if (e + 3 != self_k) mn = fminf(mn, d2); rk += (int)(K1.y < ki);
        }
    }
    nn2p[by * NPTS + i] = mn;   // coalesced, written exactly once
    rkp [by * NPTS + i] = rk;
}

// grid 32, block 256. Reduce partials -> nn_dist + total rank; scatter into
// pz-sorted order; per-block double partial sum of nn_dist.
__global__ __launch_bounds__(256) void k_mid(const float* __restrict__ sx,
                                             const float* __restrict__ sy,
                                             const float* __restrict__ sz,
                                             const float* __restrict__ nn2p,
                                             const int* __restrict__ rkp,
                                             float2* __restrict__ pxy,
                                             float* __restrict__ pzs,
                                             double* __restrict__ sum_part) {
    const int t = threadIdx.x;
    const int i = blockIdx.x * 256 + t;
    float mn = 3.0e38f;
    int rk = 0;
    #pragma unroll 8
    for (int s = 0; s < NSL; ++s) {
        mn = fminf(mn, nn2p[s * NPTS + i]);   // coalesced across threads
        rk += rkp[s * NPTS + i];
    }
    // clamp commutes with min across slices: min_s max(m_s,0) == max(min_s,0)
    const float nnd = sqrtf(fmaxf(mn, 0.0f));
    pxy[rk] = make_float2(sx[i], sy[i]);
    pzs[rk] = sz[i];

    double acc = (double)nnd;
    #pragma unroll
    for (int off = 32; off > 0; off >>= 1) acc += __shfl_down(acc, off, 64);
    __shared__ double sw[4];
    if ((t & 63) == 0) sw[t >> 6] = acc;
    __syncthreads();
    if (t == 0) sum_part[blockIdx.x] = sw[0] + sw[1] + sw[2] + sw[3];
}

// One block per (row, group of 8 cols): 12x96 blocks. Thread t owns point
// 256k+t of chunk k (pz-sorted) -> coalesced float2 loads. Membership as
// per-wave 64-bit ballots in LDS; rank selection per-wave in the epilogue.
// delta2 finalized per-block from the 32 double partials (deterministic ->
// identical in every block).
// NOTE: replicates reference exactly: px upper bound uses Yr (row-uniform), not Xr.
__global__ __launch_bounds__(256) void k_median(const float2* __restrict__ pxy,
                                                const float* __restrict__ pzs,
                                                const double* __restrict__ sum_part,
                                                float* __restrict__ out) {
    __shared__ unsigned long long bal[8][4][32];  // [cell][wave][chunk]
    __shared__ float s_dd;
    const int t = threadIdx.x;
    const int lane = t & 63;
    const int w = t >> 6;
    const int row = blockIdx.y;      // 96
    const int cg = blockIdx.x;       // 12 col-groups of 8
    if (t == 0) {
        double s = 0.0;
        #pragma unroll
        for (int b = 0; b < 32; ++b) s += sum_part[b];
        float mean = (float)(s / (double)NPTS);
        float avg = 3.0f * mean;     // M_FACTOR * mean
        s_dd = 3.0f * avg;           // M_FACTOR * avg
    }
    __syncthreads();
    const float d = s_dd;
    const float Yf = (float)(row - 48);
    const float ylo = Yf - d, yhi = Yf + d, xhi = Yf + d;
    float xlo[8];
    #pragma unroll
    for (int c = 0; c < 8; ++c) xlo[c] = (float)(cg * 8 + c - 48) - d;

    #pragma unroll 4
    for (int k = 0; k < 32; ++k) {
        float2 p = pxy[(k << 8) + t];
        bool pre = (p.y >= ylo) && (p.y <= yhi) && (p.x <= xhi);
        unsigned long long b[8];
        #pragma unroll
        for (int c = 0; c < 8; ++c) b[c] = __ballot(pre && (p.x >= xlo[c]));
        if (lane == 0) {
            #pragma unroll
            for (int c = 0; c < 8; ++c) bal[c][w][k] = b[c];
        }
    }
    __syncthreads();

    // wave w handles cells 2w and 2w+1; lanes 0..31 each own one chunk
    #pragma unroll
    for (int c2 = 0; c2 < 2; ++c2) {
        const int c = w * 2 + c2;
        const int l = (lane < 32) ? lane : 31;
        const unsigned long long bw0 = bal[c][0][l];
        const unsigned long long bw1 = bal[c][1][l];
        const unsigned long long bw2 = bal[c][2][l];
        const unsigned long long bw3 = bal[c][3][l];
        const int cnt = __popcll(bw0) + __popcll(bw1) + __popcll(bw2) + __popcll(bw3);
        const int cl = (lane < 32) ? cnt : 0;
        int incl = cl;
        #pragma unroll
        for (int off = 1; off < 64; off <<= 1) {
            int v = __shfl_up(incl, off, 64);
            if (lane >= off) incl += v;
        }
        const int ct = __shfl(incl, 63, 64);  // total count c
        const int og = row * 96 + cg * 8 + c;
        if (ct == 0) {
            if (lane == 0) out[og] = 0.0f;
            continue;
        }
        const int excl = incl - cl;
        float vv[2];
        #pragma unroll
        for (int sel = 0; sel < 2; ++sel) {
            const int target = sel ? (ct >> 1) : ((ct - 1) >> 1);
            const bool pred = (lane < 32) && (target >= excl) && (target < excl + cl);
            unsigned long long bm = __ballot(pred);
            int src = __ffsll(bm) - 1;  // exactly one lane holds the target
            float val = 0.0f;
            if (pred) {
                int r = target - excl;
                int pc0 = __popcll(bw0), pc1 = __popcll(bw1), pc2 = __popcll(bw2);
                unsigned long long x;
                int base;
                if (r < pc0)              { x = bw0; base = 0; }
                else if (r < pc0 + pc1)   { x = bw1; base = 64;  r -= pc0; }
                else if (r < pc0+pc1+pc2) { x = bw2; base = 128; r -= pc0 + pc1; }
                else                      { x = bw3; base = 192; r -= pc0 + pc1 + pc2; }
                for (int q = 0; q < r; ++q) x &= x - 1;  // drop r lowest set bits
                val = pzs[(l << 8) + base + (__ffsll(x) - 1)];
            }
            vv[sel] = __shfl(val, src, 64);
        }
        if (lane == 0) {
            float med = 0.5f * (vv[0] + vv[1]);
            out[og] = (med + 48.0f) * (1.0f / 96.0f);
        }
    }
}

extern "C" void kernel_launch(void* const* d_in, const int* in_sizes, int n_in,
                              void* d_out, int out_size, void* d_ws, size_t ws_size,
                              hipStream_t stream) {
    const float* pts = (const float*)d_in[0];
    float* out = (float*)d_out;

    char* ws = (char*)d_ws;
    float* nn2p      = (float*)(ws + 0);
    int* rkp         = (int*)(ws + 2097152);
    float2* pxy      = (float2*)(ws + 4194304);
    float* pzs       = (float*)(ws + 4259840);
    double* sum_part = (double*)(ws + 4292608);
    float* sx        = (float*)(ws + 4325376);
    float* sy        = (float*)(ws + 4358144);
    float* sz        = (float*)(ws + 4390912);
    float* ssq       = (float*)(ws + 4423680);
    unsigned long long* skey = (unsigned long long*)(ws + 4456448);

    k_soa<<<32, 256, 0, stream>>>(pts, sx, sy, sz, ssq, skey);
    k_nn_rank<<<dim3(32, NSL), 256, 0, stream>>>(sx, sy, sz, ssq, skey, nn2p, rkp);
    k_mid<<<32, 256, 0, stream>>>(sx, sy, sz, nn2p, rkp, pxy, pzs, sum_part);
    k_median<<<dim3(12, 96), 256, 0, stream>>>(pxy, pzs, sum_part, out);
}

// Round 2
// 99.167 us; speedup vs baseline: 1.0822x; 1.0796x over previous
//
#include <hip/hip_runtime.h>

#define NPTS 8192
#define NSL 64          // j-slices (128 points each)
#define HF 96.0f

typedef float v4f __attribute__((ext_vector_type(4)));
typedef int   v4i __attribute__((ext_vector_type(4)));

// Workspace layout (bytes):
//   0        : float  nn2p[64][8192]   partial min d2 (unclamped) per (slice, i)
//   2097152  : int    rkp [64][8192]   partial pz-rank per (slice, i)
//   4194304  : float2 pxy[8192]        (px,py) sorted by pz
//   4259840  : float  pzs[8192]
//   4292608  : double sum_part[32]     per-block partial sums of nn_dist
//   4325376  : float  sx[8192]         SoA: x*HF
//   4358144  : float  sy[8192]
//   4390912  : float  sz[8192]
//   4423680  : float  ssq[8192]        x^2+y^2+z^2
//   4456448  : u64    skey[8192]       monotone (z, idx) sort key
// Session lessons: coop grid.sync ~100us/sync -> keep separate launches.
// 16-col k_median regressed -> keep 8-col.
// R1: DS-broadcast vs scalar-load inner loop was NEUTRAL (107.3 -> 107.1) =>
//     k_nn_rank memory path not critical; ~80 us of the window is the harness
//     256 MiB workspace poison (2x 40us fills at 84% HBM peak, roofline).
// R2 (this): pack the d2 chain as v4f -> v_pk_fma_f32/v_pk_add_f32 (VOP3P),
//     ~30% fewer inner-loop VALU insts. Bit-exact: identical op association
//     per element; min/sum reassociation is value-exact for f32 (no NaN).

// monotone (z, idx) -> u64 key; strict total order, one u64 compare per pair
__device__ __forceinline__ unsigned long long zkey(float z, int idx) {
    unsigned u = __float_as_uint(z);
    unsigned m = (unsigned)((int)u >> 31) | 0x80000000u;  // neg: FFFFFFFF, pos: 80000000
    return ((unsigned long long)(u ^ m) << 13) | (unsigned)idx;
}

// SoA prep: 32 blocks x 256. Bit-identical values to the original fused compute.
__global__ __launch_bounds__(256) void k_soa(const float* __restrict__ pts,
                                             float* __restrict__ sx,
                                             float* __restrict__ sy,
                                             float* __restrict__ sz,
                                             float* __restrict__ ssq,
                                             unsigned long long* __restrict__ skey) {
    const int i = blockIdx.x * 256 + threadIdx.x;
    const float x = pts[3 * i + 0] * HF;
    const float y = pts[3 * i + 1] * HF;
    const float z = pts[3 * i + 2] * HF;
    sx[i] = x; sy[i] = y; sz[i] = z;
    ssq[i] = x * x + y * y + z * z;
    skey[i] = zkey(z, i);
}

// grid (32 i-blocks, 64 j-slices of 128), block 256 -> 2048 blocks, 8/CU.
// j-operands wave-uniform -> scalar-cache loads; d2 chain packed (v_pk_*_f32).
__global__ __launch_bounds__(256) void k_nn_rank(const float* __restrict__ sx,
                                                 const float* __restrict__ sy,
                                                 const float* __restrict__ sz,
                                                 const float* __restrict__ ssq,
                                                 const unsigned long long* __restrict__ skey,
                                                 float* __restrict__ nn2p,
                                                 int* __restrict__ rkp) {
    const int tid = threadIdx.x;
    const int bx = blockIdx.x, by = blockIdx.y;
    const int i = bx * 256 + tid;

    const float xi = sx[i], yi = sy[i], zi = sz[i], sqi = ssq[i];
    const unsigned long long ki = skey[i];

    // uniform (wave-invariant) j-slice base pointers, 16B-aligned
    const v4f* __restrict__ vx = (const v4f*)sx + by * 32;
    const v4f* __restrict__ vy = (const v4f*)sy + by * 32;
    const v4f* __restrict__ vz = (const v4f*)sz + by * 32;
    const v4f* __restrict__ vq = (const v4f*)ssq + by * 32;
    const ulonglong2* __restrict__ vk = (const ulonglong2*)skey + by * 64;

    v4f mn4 = {3.0e38f, 3.0e38f, 3.0e38f, 3.0e38f};
    int rk = 0;
    // self-pair occurs iff this j-slice covers i; condition is wave-uniform
    // (tid>>7 constant within a wave), so no divergence between loop versions.
    const bool has_self = (by == 2 * bx + (tid >> 7));
    if (!has_self) {
        #pragma unroll 8
        for (int kb = 0; kb < 32; ++kb) {
            const v4f X = vx[kb], Y = vy[kb], Z = vz[kb], Q = vq[kb];
            const ulonglong2 K0 = vk[2 * kb], K1 = vk[2 * kb + 1];
            // reference formula per element: sq_i + sq_j - 2*dot  (packed 4-wide)
            v4f d2 = sqi + Q - 2.0f * (xi * X + yi * Y + zi * Z);
            mn4 = __builtin_elementwise_min(mn4, d2);
            rk += (int)(K0.x < ki) + (int)(K0.y < ki) + (int)(K1.x < ki) + (int)(K1.y < ki);
        }
    } else {
        const int self_k = tid & 127;   // j - j0 of the self pair (per-lane)
        const v4i sk4 = {self_k, self_k, self_k, self_k};
        #pragma unroll 8
        for (int kb = 0; kb < 32; ++kb) {
            const v4f X = vx[kb], Y = vy[kb], Z = vz[kb], Q = vq[kb];
            const ulonglong2 K0 = vk[2 * kb], K1 = vk[2 * kb + 1];
            v4f d2 = sqi + Q - 2.0f * (xi * X + yi * Y + zi * Z);
            const int e = kb * 4;
            const v4i ev = {e, e + 1, e + 2, e + 3};
            const v4f big = {3.0e38f, 3.0e38f, 3.0e38f, 3.0e38f};
            d2 = (ev == sk4) ? big : d2;   // exclude self (elementwise cndmask)
            mn4 = __builtin_elementwise_min(mn4, d2);
            rk += (int)(K0.x < ki) + (int)(K0.y < ki) + (int)(K1.x < ki) + (int)(K1.y < ki);
        }
    }
    // horizontal min: f32 min is associative/commutative (no NaN) -> exact
    const float mn = fminf(fminf(mn4.x, mn4.y), fminf(mn4.z, mn4.w));
    nn2p[by * NPTS + i] = mn;   // coalesced, written exactly once
    rkp [by * NPTS + i] = rk;
}

// grid 32, block 256. Reduce partials -> nn_dist + total rank; scatter into
// pz-sorted order; per-block double partial sum of nn_dist.
__global__ __launch_bounds__(256) void k_mid(const float* __restrict__ sx,
                                             const float* __restrict__ sy,
                                             const float* __restrict__ sz,
                                             const float* __restrict__ nn2p,
                                             const int* __restrict__ rkp,
                                             float2* __restrict__ pxy,
                                             float* __restrict__ pzs,
                                             double* __restrict__ sum_part) {
    const int t = threadIdx.x;
    const int i = blockIdx.x * 256 + t;
    float mn = 3.0e38f;
    int rk = 0;
    #pragma unroll 8
    for (int s = 0; s < NSL; ++s) {
        mn = fminf(mn, nn2p[s * NPTS + i]);   // coalesced across threads
        rk += rkp[s * NPTS + i];
    }
    // clamp commutes with min across slices: min_s max(m_s,0) == max(min_s,0)
    const float nnd = sqrtf(fmaxf(mn, 0.0f));
    pxy[rk] = make_float2(sx[i], sy[i]);
    pzs[rk] = sz[i];

    double acc = (double)nnd;
    #pragma unroll
    for (int off = 32; off > 0; off >>= 1) acc += __shfl_down(acc, off, 64);
    __shared__ double sw[4];
    if ((t & 63) == 0) sw[t >> 6] = acc;
    __syncthreads();
    if (t == 0) sum_part[blockIdx.x] = sw[0] + sw[1] + sw[2] + sw[3];
}

// One block per (row, group of 8 cols): 12x96 blocks. Thread t owns point
// 256k+t of chunk k (pz-sorted) -> coalesced float2 loads. Membership as
// per-wave 64-bit ballots in LDS; rank selection per-wave in the epilogue.
// delta2 finalized per-block from the 32 double partials (deterministic ->
// identical in every block).
// NOTE: replicates reference exactly: px upper bound uses Yr (row-uniform), not Xr.
__global__ __launch_bounds__(256) void k_median(const float2* __restrict__ pxy,
                                                const float* __restrict__ pzs,
                                                const double* __restrict__ sum_part,
                                                float* __restrict__ out) {
    __shared__ unsigned long long bal[8][4][32];  // [cell][wave][chunk]
    __shared__ float s_dd;
    const int t = threadIdx.x;
    const int lane = t & 63;
    const int w = t >> 6;
    const int row = blockIdx.y;      // 96
    const int cg = blockIdx.x;       // 12 col-groups of 8
    if (t == 0) {
        double s = 0.0;
        #pragma unroll
        for (int b = 0; b < 32; ++b) s += sum_part[b];
        float mean = (float)(s / (double)NPTS);
        float avg = 3.0f * mean;     // M_FACTOR * mean
        s_dd = 3.0f * avg;           // M_FACTOR * avg
    }
    __syncthreads();
    const float d = s_dd;
    const float Yf = (float)(row - 48);
    const float ylo = Yf - d, yhi = Yf + d, xhi = Yf + d;
    float xlo[8];
    #pragma unroll
    for (int c = 0; c < 8; ++c) xlo[c] = (float)(cg * 8 + c - 48) - d;

    #pragma unroll 4
    for (int k = 0; k < 32; ++k) {
        float2 p = pxy[(k << 8) + t];
        bool pre = (p.y >= ylo) && (p.y <= yhi) && (p.x <= xhi);
        unsigned long long b[8];
        #pragma unroll
        for (int c = 0; c < 8; ++c) b[c] = __ballot(pre && (p.x >= xlo[c]));
        if (lane == 0) {
            #pragma unroll
            for (int c = 0; c < 8; ++c) bal[c][w][k] = b[c];
        }
    }
    __syncthreads();

    // wave w handles cells 2w and 2w+1; lanes 0..31 each own one chunk
    #pragma unroll
    for (int c2 = 0; c2 < 2; ++c2) {
        const int c = w * 2 + c2;
        const int l = (lane < 32) ? lane : 31;
        const unsigned long long bw0 = bal[c][0][l];
        const unsigned long long bw1 = bal[c][1][l];
        const unsigned long long bw2 = bal[c][2][l];
        const unsigned long long bw3 = bal[c][3][l];
        const int cnt = __popcll(bw0) + __popcll(bw1) + __popcll(bw2) + __popcll(bw3);
        const int cl = (lane < 32) ? cnt : 0;
        int incl = cl;
        #pragma unroll
        for (int off = 1; off < 64; off <<= 1) {
            int v = __shfl_up(incl, off, 64);
            if (lane >= off) incl += v;
        }
        const int ct = __shfl(incl, 63, 64);  // total count c
        const int og = row * 96 + cg * 8 + c;
        if (ct == 0) {
            if (lane == 0) out[og] = 0.0f;
            continue;
        }
        const int excl = incl - cl;
        float vv[2];
        #pragma unroll
        for (int sel = 0; sel < 2; ++sel) {
            const int target = sel ? (ct >> 1) : ((ct - 1) >> 1);
            const bool pred = (lane < 32) && (target >= excl) && (target < excl + cl);
            unsigned long long bm = __ballot(pred);
            int src = __ffsll(bm) - 1;  // exactly one lane holds the target
            float val = 0.0f;
            if (pred) {
                int r = target - excl;
                int pc0 = __popcll(bw0), pc1 = __popcll(bw1), pc2 = __popcll(bw2);
                unsigned long long x;
                int base;
                if (r < pc0)              { x = bw0; base = 0; }
                else if (r < pc0 + pc1)   { x = bw1; base = 64;  r -= pc0; }
                else if (r < pc0+pc1+pc2) { x = bw2; base = 128; r -= pc0 + pc1; }
                else                      { x = bw3; base = 192; r -= pc0 + pc1 + pc2; }
                for (int q = 0; q < r; ++q) x &= x - 1;  // drop r lowest set bits
                val = pzs[(l << 8) + base + (__ffsll(x) - 1)];
            }
            vv[sel] = __shfl(val, src, 64);
        }
        if (lane == 0) {
            float med = 0.5f * (vv[0] + vv[1]);
            out[og] = (med + 48.0f) * (1.0f / 96.0f);
        }
    }
}

extern "C" void kernel_launch(void* const* d_in, const int* in_sizes, int n_in,
                              void* d_out, int out_size, void* d_ws, size_t ws_size,
                              hipStream_t stream) {
    const float* pts = (const float*)d_in[0];
    float* out = (float*)d_out;

    char* ws = (char*)d_ws;
    float* nn2p      = (float*)(ws + 0);
    int* rkp         = (int*)(ws + 2097152);
    float2* pxy      = (float2*)(ws + 4194304);
    float* pzs       = (float*)(ws + 4259840);
    double* sum_part = (double*)(ws + 4292608);
    float* sx        = (float*)(ws + 4325376);
    float* sy        = (float*)(ws + 4358144);
    float* sz        = (float*)(ws + 4390912);
    float* ssq       = (float*)(ws + 4423680);
    unsigned long long* skey = (unsigned long long*)(ws + 4456448);

    k_soa<<<32, 256, 0, stream>>>(pts, sx, sy, sz, ssq, skey);
    k_nn_rank<<<dim3(32, NSL), 256, 0, stream>>>(sx, sy, sz, ssq, skey, nn2p, rkp);
    k_mid<<<32, 256, 0, stream>>>(sx, sy, sz, nn2p, rkp, pxy, pzs, sum_part);
    k_median<<<dim3(12, 96), 256, 0, stream>>>(pxy, pzs, sum_part, out);
}